// Round 1
// baseline (383.682 us; speedup 1.0000x reference)
//
#include <hip/hip_runtime.h>
#include <math.h>

#define NC 4096

// ---------------- Kernel 1: accumulate per-cluster moments ----------------
// LDS layout SoA: s[k*NC + id], k in 0..9 = {cnt, sx, sy, sz, sxx, sxy, sxz, syy, syz, szz}
// bank = id % 32 -> random ids spread across all 32 banks (2-way avg = free).
__global__ __launch_bounds__(1024) void k_accum(const float* __restrict__ data,
                                                const int* __restrict__ ids,
                                                float* __restrict__ gmom, int n) {
    extern __shared__ float s[];  // 10 * NC floats = 160 KiB
    for (int i = threadIdx.x; i < 10 * NC; i += blockDim.x) s[i] = 0.0f;
    __syncthreads();

    int stride = gridDim.x * blockDim.x;
    for (int i = blockIdx.x * blockDim.x + threadIdx.x; i < n; i += stride) {
        int id = ids[i];
        float x = data[i * 5 + 0];
        float y = data[i * 5 + 1];
        float z = data[i * 5 + 2];
        atomicAdd(&s[0 * NC + id], 1.0f);
        atomicAdd(&s[1 * NC + id], x);
        atomicAdd(&s[2 * NC + id], y);
        atomicAdd(&s[3 * NC + id], z);
        atomicAdd(&s[4 * NC + id], x * x);
        atomicAdd(&s[5 * NC + id], x * y);
        atomicAdd(&s[6 * NC + id], x * z);
        atomicAdd(&s[7 * NC + id], y * y);
        atomicAdd(&s[8 * NC + id], y * z);
        atomicAdd(&s[9 * NC + id], z * z);
    }
    __syncthreads();
    for (int i = threadIdx.x; i < 10 * NC; i += blockDim.x) {
        float v = s[i];
        if (v != 0.0f) atomicAdd(&gmom[i], v);
    }
}

// ---------------- Kernel 2: per-cluster eigensolve + B/center/count ----------------
__global__ void k_eigen(const float* __restrict__ gmom, float* __restrict__ out,
                        float* __restrict__ params) {
    int c = blockIdx.x * blockDim.x + threadIdx.x;
    if (c >= NC) return;

    float cnt = gmom[0 * NC + c];
    float sx  = gmom[1 * NC + c], sy  = gmom[2 * NC + c], sz  = gmom[3 * NC + c];
    float sxx = gmom[4 * NC + c], sxy = gmom[5 * NC + c], sxz = gmom[6 * NC + c];
    float syy = gmom[7 * NC + c], syz = gmom[8 * NC + c], szz = gmom[9 * NC + c];

    double dn  = (double)cnt;
    double inv = 1.0 / fmax(dn, 1.0);
    double cx = sx * inv, cy = sy * inv, cz = sz * inv;

    // cov = Sxx - n * mu mu^T  (exact identity for centered second moment)
    double a00 = (double)sxx - dn * cx * cx;
    double a01 = (double)sxy - dn * cx * cy;
    double a02 = (double)sxz - dn * cx * cz;
    double a11 = (double)syy - dn * cy * cy;
    double a12 = (double)syz - dn * cy * cz;
    double a22 = (double)szz - dn * cz * cz;

    // --- eigenvalues: Smith's trigonometric method ---
    double q  = (a00 + a11 + a22) / 3.0;
    double p1 = a01 * a01 + a02 * a02 + a12 * a12;
    double b00 = a00 - q, b11 = a11 - q, b22 = a22 - q;
    double p2 = b00 * b00 + b11 * b11 + b22 * b22 + 2.0 * p1;
    double w0, w1, w2;
    if (!(p2 > 0.0)) {
        w0 = w1 = w2 = q;
    } else {
        double p  = sqrt(p2 / 6.0);
        double ip = 1.0 / p;
        double c00 = b00 * ip, c01 = a01 * ip, c02 = a02 * ip;
        double c11 = b11 * ip, c12 = a12 * ip, c22 = b22 * ip;
        double detB = c00 * (c11 * c22 - c12 * c12)
                    - c01 * (c01 * c22 - c12 * c02)
                    + c02 * (c01 * c12 - c11 * c02);
        double r = detB * 0.5;
        r = fmin(1.0, fmax(-1.0, r));
        double phi = acos(r) / 3.0;
        w2 = q + 2.0 * p * cos(phi);                          // largest
        w0 = q + 2.0 * p * cos(phi + 2.0943951023931953);     // smallest (+2pi/3)
        w1 = 3.0 * q - w2 - w0;                               // middle
    }

    double denom = (w2 == 0.0) ? 1.0 : w2;
    double dirwt = (w2 == 0.0) ? 0.0 : (1.0 - w1 / w2);

    // --- eigenvector of largest eigenvalue: columns of (A - w1 I)(A - w0 I) ---
    double C00 = a00 - w1, C11 = a11 - w1, C22 = a22 - w1;
    double D00 = a00 - w0, D11 = a11 - w0, D22 = a22 - w0;
    double M00 = C00 * D00 + a01 * a01 + a02 * a02;
    double M10 = a01 * D00 + C11 * a01 + a12 * a02;
    double M20 = a02 * D00 + a12 * a01 + C22 * a02;
    double M01 = C00 * a01 + a01 * D11 + a02 * a12;
    double M11 = a01 * a01 + C11 * D11 + a12 * a12;
    double M21 = a02 * a01 + a12 * D11 + C22 * a12;
    double M02 = C00 * a02 + a01 * a12 + a02 * D22;
    double M12 = a01 * a02 + C11 * a12 + a12 * D22;
    double M22 = a02 * a02 + a12 * a12 + C22 * D22;
    double n0 = M00 * M00 + M10 * M10 + M20 * M20;
    double n1 = M01 * M01 + M11 * M11 + M21 * M21;
    double n2 = M02 * M02 + M12 * M12 + M22 * M22;
    double vx, vy, vz, nn;
    if (n0 >= n1 && n0 >= n2) { vx = M00; vy = M10; vz = M20; nn = n0; }
    else if (n1 >= n2)        { vx = M01; vy = M11; vz = M21; nn = n1; }
    else                      { vx = M02; vy = M12; vz = M22; nn = n2; }
    if (nn > 1e-300) {
        double rn = 1.0 / sqrt(nn);
        vx *= rn; vy *= rn; vz *= rn;
    } else {
        vx = vy = vz = 0.0;
    }

    bool small = cnt < 2.0f;
    float bscale = small ? 0.0f : (float)(1.0 / denom);

    float* o = out + c * 16;
    o[0]  = (float)cx;
    o[1]  = (float)cy;
    o[2]  = (float)cz;
    o[3]  = (float)a00 * bscale;
    o[4]  = (float)a01 * bscale;
    o[5]  = (float)a02 * bscale;
    o[6]  = (float)a01 * bscale;
    o[7]  = (float)a11 * bscale;
    o[8]  = (float)a12 * bscale;
    o[9]  = (float)a02 * bscale;
    o[10] = (float)a12 * bscale;
    o[11] = (float)a22 * bscale;
    o[15] = cnt;

    params[0 * NC + c] = (float)cx;
    params[1 * NC + c] = (float)cy;
    params[2 * NC + c] = (float)cz;
    params[3 * NC + c] = (float)vx;
    params[4 * NC + c] = (float)vy;
    params[5 * NC + c] = (float)vz;
    params[6 * NC + c] = (float)dirwt;
    params[7 * NC + c] = cnt;
}

// ---------------- Kernel 3: second voxel pass, sc = seg(x0 * ||xp0||) ----------------
__global__ __launch_bounds__(1024) void k_sc(const float* __restrict__ data,
                                             const int* __restrict__ ids,
                                             const float* __restrict__ params,
                                             float* __restrict__ gsc, int n) {
    extern __shared__ float sl[];     // 6*NC params staged + NC sc bins = 112 KiB
    float* ssc = sl + 6 * NC;
    for (int i = threadIdx.x; i < 6 * NC; i += blockDim.x) sl[i] = params[i];
    for (int i = threadIdx.x; i < NC; i += blockDim.x) ssc[i] = 0.0f;
    __syncthreads();

    int stride = gridDim.x * blockDim.x;
    for (int i = blockIdx.x * blockDim.x + threadIdx.x; i < n; i += stride) {
        int id = ids[i];
        float x = data[i * 5 + 0];
        float y = data[i * 5 + 1];
        float z = data[i * 5 + 2];
        float xc = x - sl[0 * NC + id];
        float yc = y - sl[1 * NC + id];
        float zc = z - sl[2 * NC + id];
        float vx = sl[3 * NC + id];
        float vy = sl[4 * NC + id];
        float vz = sl[5 * NC + id];
        float x0 = xc * vx + yc * vy + zc * vz;
        float px = xc - x0 * vx;
        float py = yc - x0 * vy;
        float pz = zc - x0 * vz;
        float np0 = sqrtf(px * px + py * py + pz * pz);
        atomicAdd(&ssc[id], x0 * np0);
    }
    __syncthreads();
    for (int i = threadIdx.x; i < NC; i += blockDim.x) {
        float v = ssc[i];
        if (v != 0.0f) atomicAdd(&gsc[i], v);
    }
}

// ---------------- Kernel 4: finalize v0 ----------------
__global__ void k_final(const float* __restrict__ params, const float* __restrict__ gsc,
                        float* __restrict__ out) {
    int c = blockIdx.x * blockDim.x + threadIdx.x;
    if (c >= NC) return;
    float vx = params[3 * NC + c], vy = params[4 * NC + c], vz = params[5 * NC + c];
    float dirwt = params[6 * NC + c], cnt = params[7 * NC + c];
    float sc = gsc[c];
    float s = (sc < 0.0f) ? -dirwt : dirwt;
    if (cnt < 2.0f) s = 0.0f;
    out[c * 16 + 12] = vx * s;
    out[c * 16 + 13] = vy * s;
    out[c * 16 + 14] = vz * s;
}

extern "C" void kernel_launch(void* const* d_in, const int* in_sizes, int n_in,
                              void* d_out, int out_size, void* d_ws, size_t ws_size,
                              hipStream_t stream) {
    const float* data = (const float*)d_in[0];
    const int*   ids  = (const int*)d_in[1];
    float* out = (float*)d_out;
    int n = in_sizes[1];  // number of voxels (clust_ids count)

    char* ws = (char*)d_ws;
    float* gmom   = (float*)(ws);                       // 10*NC floats
    float* gsc    = (float*)(ws + 10 * NC * 4);         // NC floats
    float* params = (float*)(ws + 11 * NC * 4);         // 8*NC floats

    // zero moment + sc accumulators (params fully overwritten by k_eigen)
    hipMemsetAsync(ws, 0, 11 * NC * 4, stream);

    hipLaunchKernelGGL(k_accum, dim3(256), dim3(1024), 10 * NC * 4, stream,
                       data, ids, gmom, n);
    hipLaunchKernelGGL(k_eigen, dim3(16), dim3(256), 0, stream,
                       gmom, out, params);
    hipLaunchKernelGGL(k_sc, dim3(256), dim3(1024), 7 * NC * 4, stream,
                       data, ids, params, gsc, n);
    hipLaunchKernelGGL(k_final, dim3(16), dim3(256), 0, stream,
                       params, gsc, out);
}